// Round 1
// baseline (817.762 us; speedup 1.0000x reference)
//
#include <hip/hip_runtime.h>
#include <cstdint>
#include <cstddef>

#define S_ 2048
#define D_ 64
#define SSTR 2056   // 2048 + 8 pad (bf16 elems) -> row stride 4112 B, 16B-aligned, banks +4
#define VSTR 136    // 128 + 8 pad -> row stride 272 B, 16B-aligned, banks +4

typedef __attribute__((ext_vector_type(4))) float f32x4;
typedef __attribute__((ext_vector_type(2))) float f32x2;
typedef __attribute__((ext_vector_type(8))) __bf16 bf16x8;
typedef __attribute__((ext_vector_type(8))) unsigned short us8;
typedef __attribute__((ext_vector_type(2))) unsigned short us2;

static __device__ __forceinline__ unsigned short f2bf(float f) {
  unsigned int u = __builtin_bit_cast(unsigned int, f);
  u += 0x7fffu + ((u >> 16) & 1u);          // RNE (no NaNs in this problem)
  return (unsigned short)(u >> 16);
}
static __device__ __forceinline__ float bf2f(unsigned short h) {
  unsigned int u = ((unsigned int)h) << 16;
  return __builtin_bit_cast(float, u);
}
static __device__ __forceinline__ bf16x8 cvt8(const float* p) {
  f32x4 a = *(const f32x4*)p;
  f32x4 b = *(const f32x4*)(p + 4);
  us8 t;
  t[0]=f2bf(a[0]); t[1]=f2bf(a[1]); t[2]=f2bf(a[2]); t[3]=f2bf(a[3]);
  t[4]=f2bf(b[0]); t[5]=f2bf(b[1]); t[6]=f2bf(b[2]); t[7]=f2bf(b[3]);
  return __builtin_bit_cast(bf16x8, t);
}

__global__ __launch_bounds__(512)
void attn_kernel(const float* __restrict__ Q, const float* __restrict__ K,
                 const float* __restrict__ V, const int* __restrict__ M,
                 float* __restrict__ outO, float* __restrict__ outP)
{
  __shared__ __align__(16) unsigned short sS[32][SSTR];   // 131584 B raw scores -> P (bf16)
  __shared__ __align__(16) unsigned short sV[D_][VSTR];   // 17408 B  V chunk, transposed [d][k]
  __shared__ float sM[32];
  __shared__ float sR[32];

  const int tid  = threadIdx.x;
  const int wid  = tid >> 6;
  const int lane = tid & 63;
  const int l15  = lane & 15;
  const int l4   = lane >> 4;

  // XCD swizzle: 4096 blocks = 8 * 512 (bijective). Each XCD gets 8 consecutive heads.
  const int bid = ((blockIdx.x & 7) << 9) | (blockIdx.x >> 3);
  const int bh = bid >> 6;     // 0..63  (b*16 + h)
  const int qt = bid & 63;     // Q tile of 32 rows
  const int b  = bh >> 4;

  const float* Qh = Q + ((size_t)bh * S_ + (size_t)qt * 32) * D_;
  const float* Kh = K + (size_t)bh * S_ * D_;
  const float* Vh = V + (size_t)bh * S_ * D_;
  const int*   Mb = M + (size_t)b * S_;
  float* Ph = outP + (size_t)bh * S_ * S_ + (size_t)qt * 32 * S_;
  float* Oh = outO + ((size_t)bh * S_ + (size_t)qt * 32) * D_;

  // ---------- Phase 1: scores = mask(Q K^T / 8) -> sS (bf16) ----------
  bf16x8 qa[2][2];
#pragma unroll
  for (int rt = 0; rt < 2; ++rt)
#pragma unroll
    for (int s = 0; s < 2; ++s)
      qa[rt][s] = cvt8(Qh + (rt*16 + l15)*D_ + s*32 + l4*8);

  for (int i = 0; i < 16; ++i) {
    const int col0 = (wid*16 + i) * 16;          // wave owns cols [wid*256, wid*256+256)
    const int mk = Mb[col0 + l15];
    const float* kp = Kh + (size_t)(col0 + l15)*D_ + l4*8;
    bf16x8 kf0 = cvt8(kp);
    bf16x8 kf1 = cvt8(kp + 32);
    f32x4 acc0 = {0.f,0.f,0.f,0.f}, acc1 = {0.f,0.f,0.f,0.f};
    acc0 = __builtin_amdgcn_mfma_f32_16x16x32_bf16(qa[0][0], kf0, acc0, 0,0,0);
    acc0 = __builtin_amdgcn_mfma_f32_16x16x32_bf16(qa[0][1], kf1, acc0, 0,0,0);
    acc1 = __builtin_amdgcn_mfma_f32_16x16x32_bf16(qa[1][0], kf0, acc1, 0,0,0);
    acc1 = __builtin_amdgcn_mfma_f32_16x16x32_bf16(qa[1][1], kf1, acc1, 0,0,0);
#pragma unroll
    for (int r = 0; r < 4; ++r) {                 // C layout: col=l&15, row=(l>>4)*4+r
      float s0 = (mk == 0) ? -1.0e9f : acc0[r]*0.125f;
      float s1 = (mk == 0) ? -1.0e9f : acc1[r]*0.125f;
      sS[     l4*4 + r][col0 + l15] = f2bf(s0);
      sS[16 + l4*4 + r][col0 + l15] = f2bf(s1);
    }
  }
  __syncthreads();

  // ---------- Phase 2: row max & exp-sum (16 lanes per row) ----------
  {
    const int row = tid >> 4;
    const int sub = tid & 15;
    float mx = -3.0e38f;
#pragma unroll 4
    for (int j = 0; j < 16; ++j) {
      us8 v = *(const us8*)&sS[row][j*128 + sub*8];
#pragma unroll
      for (int k = 0; k < 8; ++k) mx = fmaxf(mx, bf2f(v[k]));
    }
#pragma unroll
    for (int o = 1; o < 16; o <<= 1) mx = fmaxf(mx, __shfl_xor(mx, o));
    float sm = 0.f;
#pragma unroll 4
    for (int j = 0; j < 16; ++j) {
      us8 v = *(const us8*)&sS[row][j*128 + sub*8];
#pragma unroll
      for (int k = 0; k < 8; ++k) sm += __expf(bf2f(v[k]) - mx);
    }
#pragma unroll
    for (int o = 1; o < 16; o <<= 1) sm += __shfl_xor(sm, o);
    if (sub == 0) { sM[row] = mx; sR[row] = 1.0f / sm; }
  }
  __syncthreads();

  float rowM[4], rowR[4];
#pragma unroll
  for (int r = 0; r < 4; ++r) { rowM[r] = sM[wid*4 + r]; rowR[r] = sR[wid*4 + r]; }

  // ---------- Phase 3: per 128-col chunk: {stage V, write P} -> barrier -> PV ----------
  const int rt = wid >> 2, dt = wid & 3;
  f32x4 oacc = {0.f,0.f,0.f,0.f};

  for (int kc = 0; kc < 16; ++kc) {
    const int kb0 = kc * 128;
    // (A) stage V chunk, transposed to [d][k] bf16 (coalesced 16B/lane global reads)
#pragma unroll
    for (int ps = 0; ps < 4; ++ps) {
      int idx = ps*512 + tid;
      int kl  = idx >> 4;
      int d4  = (idx & 15) << 2;
      f32x4 v = *(const f32x4*)&Vh[(size_t)(kb0 + kl)*D_ + d4];
      sV[d4+0][kl] = f2bf(v[0]);
      sV[d4+1][kl] = f2bf(v[1]);
      sV[d4+2][kl] = f2bf(v[2]);
      sV[d4+3][kl] = f2bf(v[3]);
    }
    // (B) normalize + stream P for this chunk's cols (coalesced 512B/row stores),
    //     write bf16 P back into sS in place for the MFMA A-operand
#pragma unroll
    for (int r = 0; r < 4; ++r) {
      const int row = wid*4 + r;
      const int c = kb0 + lane*2;
      us2 v = *(const us2*)&sS[row][c];
      float p0 = __expf(bf2f(v[0]) - rowM[r]) * rowR[r];
      float p1 = __expf(bf2f(v[1]) - rowM[r]) * rowR[r];
      f32x2 pw = {p0, p1};
      *(f32x2*)&Ph[(size_t)row*S_ + c] = pw;
      us2 wb; wb[0] = f2bf(p0); wb[1] = f2bf(p1);
      *(us2*)&sS[row][c] = wb;
    }
    __syncthreads();
    // (C) PV: each wave owns one 16x16 O tile (rt = q-rows, dt = d-cols)
#pragma unroll
    for (int s = 0; s < 4; ++s) {
      const int kb = s*32 + l4*8;
      us8 pa = *(const us8*)&sS[rt*16 + l15][kb0 + kb];
      us8 vb = *(const us8*)&sV[dt*16 + l15][kb];
      oacc = __builtin_amdgcn_mfma_f32_16x16x32_bf16(
                 __builtin_bit_cast(bf16x8, pa),
                 __builtin_bit_cast(bf16x8, vb), oacc, 0,0,0);
    }
    __syncthreads();
  }

#pragma unroll
  for (int r = 0; r < 4; ++r)
    Oh[(size_t)(rt*16 + l4*4 + r)*D_ + dt*16 + l15] = oacc[r];
}

extern "C" void kernel_launch(void* const* d_in, const int* in_sizes, int n_in,
                              void* d_out, int out_size, void* d_ws, size_t ws_size,
                              hipStream_t stream) {
  const float* Q = (const float*)d_in[0];
  const float* K = (const float*)d_in[1];
  const float* V = (const float*)d_in[2];
  const int*   M = (const int*)d_in[3];
  float* outO = (float*)d_out;                                  // (B,H,S,D)
  float* outP = (float*)d_out + (size_t)4 * 16 * 2048 * 64;     // (B,H,S,S)
  attn_kernel<<<dim3(4096), dim3(512), 0, stream>>>(Q, K, V, M, outO, outP);
}

// Round 2
// 612.013 us; speedup vs baseline: 1.3362x; 1.3362x over previous
//
#include <hip/hip_runtime.h>
#include <cstdint>
#include <cstddef>

#define S_ 2048
#define D_ 64
#define PSTR 272   // sP row stride in bf16 elems (544 B, 16B-aligned)

typedef __attribute__((ext_vector_type(4))) float f32x4;
typedef __attribute__((ext_vector_type(8))) __bf16 bf16x8;
typedef __attribute__((ext_vector_type(8))) unsigned short us8;
typedef __attribute__((ext_vector_type(4))) unsigned short us4;

static __device__ __forceinline__ unsigned short f2bf(float f) {
  unsigned int u = __builtin_bit_cast(unsigned int, f);
  u += 0x7fffu + ((u >> 16) & 1u);          // RNE (no NaNs in this problem)
  return (unsigned short)(u >> 16);
}
static __device__ __forceinline__ float bf2f(unsigned short h) {
  unsigned int u = ((unsigned int)h) << 16;
  return __builtin_bit_cast(float, u);
}
static __device__ __forceinline__ bf16x8 cvt8(const float* p) {
  f32x4 a = *(const f32x4*)p;
  f32x4 b = *(const f32x4*)(p + 4);
  us8 t;
  t[0]=f2bf(a[0]); t[1]=f2bf(a[1]); t[2]=f2bf(a[2]); t[3]=f2bf(a[3]);
  t[4]=f2bf(b[0]); t[5]=f2bf(b[1]); t[6]=f2bf(b[2]); t[7]=f2bf(b[3]);
  return __builtin_bit_cast(bf16x8, t);
}

// ---------- prekernel 1: f32 -> bf16 elementwise (Q, K) ----------
__global__ __launch_bounds__(256)
void cvt_bf16_kernel(const float* __restrict__ src, unsigned short* __restrict__ dst, int n4) {
  int i = blockIdx.x * 256 + threadIdx.x;
  int stride = gridDim.x * 256;
  for (; i < n4; i += stride) {
    f32x4 v = ((const f32x4*)src)[i];
    us4 o; o[0]=f2bf(v[0]); o[1]=f2bf(v[1]); o[2]=f2bf(v[2]); o[3]=f2bf(v[3]);
    ((us4*)dst)[i] = o;
  }
}

// ---------- prekernel 2: V [bh][s][d] f32 -> Vt [bh][d][s] bf16 ----------
__global__ __launch_bounds__(256)
void vtrans_kernel(const float* __restrict__ V, unsigned short* __restrict__ Vt) {
  __shared__ unsigned short T[64][72];
  const int bh = blockIdx.x >> 5;
  const int s0 = (blockIdx.x & 31) * 64;
  const int tid = threadIdx.x;
#pragma unroll
  for (int it = 0; it < 4; ++it) {
    int idx = it * 256 + tid;
    int s = idx >> 4, d4 = (idx & 15) * 4;
    f32x4 v = *(const f32x4*)&V[((size_t)bh * S_ + s0 + s) * D_ + d4];
    T[s][d4+0] = f2bf(v[0]); T[s][d4+1] = f2bf(v[1]);
    T[s][d4+2] = f2bf(v[2]); T[s][d4+3] = f2bf(v[3]);
  }
  __syncthreads();
#pragma unroll
  for (int it = 0; it < 2; ++it) {
    int idx = it * 256 + tid;
    int d = idx >> 3, s8 = (idx & 7) * 8;
    us8 w;
#pragma unroll
    for (int j = 0; j < 8; ++j) w[j] = T[s8 + j][d];
    *(us8*)&Vt[((size_t)bh * D_ + d) * S_ + s0 + s8] = w;
  }
}

// ---------- main fused attention ----------
template<int PRE>
__global__ __launch_bounds__(512, 4)
void attn_kernel(const float* __restrict__ Q, const float* __restrict__ K,
                 const float* __restrict__ V, const int* __restrict__ M,
                 const unsigned short* __restrict__ Qb,
                 const unsigned short* __restrict__ Kb,
                 const unsigned short* __restrict__ Vt,
                 float* __restrict__ outO, float* __restrict__ outP)
{
  __shared__ __align__(16) unsigned short sP[2][32][PSTR];  // 34816 B
  __shared__ float sRed[8][32];
  __shared__ float sSum[32];

  const int tid  = threadIdx.x;
  const int wid  = tid >> 6;
  const int lane = tid & 63;
  const int l15  = lane & 15;
  const int l4   = lane >> 4;

  // XCD swizzle: 4096 blocks = 8 * 512 (bijective); heads grouped per XCD.
  const int bid = ((blockIdx.x & 7) << 9) | (blockIdx.x >> 3);
  const int bh = bid >> 6;
  const int qt = bid & 63;
  const int b  = bh >> 4;

  const float* Qh = Q + ((size_t)bh * S_ + (size_t)qt * 32) * D_;
  const float* Kh = K + (size_t)bh * S_ * D_;
  const float* Vh = V + (size_t)bh * S_ * D_;
  const int*   Mb = M + (size_t)b * S_;
  float* Ph = outP + (size_t)bh * S_ * S_ + (size_t)qt * 32 * S_;
  float* Oh = outO + ((size_t)bh * S_ + (size_t)qt * 32) * D_;

  // Q fragments (held in registers for both passes)
  bf16x8 qa[2][2];
#pragma unroll
  for (int rt = 0; rt < 2; ++rt)
#pragma unroll
    for (int sk = 0; sk < 2; ++sk) {
      if (PRE)
        qa[rt][sk] = __builtin_bit_cast(bf16x8,
          *(const us8*)&Qb[((size_t)(bh * S_ + qt*32 + rt*16 + l15)) * D_ + sk*32 + l4*8]);
      else
        qa[rt][sk] = cvt8(Qh + (rt*16 + l15) * D_ + sk*32 + l4*8);
    }

  // ---------- pass 1: row exp-sums (no score storage) ----------
  float rs[2][4] = {{0.f,0.f,0.f,0.f},{0.f,0.f,0.f,0.f}};
  for (int i = 0; i < 16; ++i) {
    const int col = wid * 256 + i * 16 + l15;
    const int mk = Mb[col];
    bf16x8 kf0, kf1;
    if (PRE) {
      const unsigned short* kp = &Kb[(size_t)(bh * S_ + col) * D_ + l4*8];
      kf0 = __builtin_bit_cast(bf16x8, *(const us8*)kp);
      kf1 = __builtin_bit_cast(bf16x8, *(const us8*)(kp + 32));
    } else {
      const float* kp = Kh + (size_t)col * D_ + l4*8;
      kf0 = cvt8(kp); kf1 = cvt8(kp + 32);
    }
    f32x4 acc0 = {0.f,0.f,0.f,0.f}, acc1 = {0.f,0.f,0.f,0.f};
    acc0 = __builtin_amdgcn_mfma_f32_16x16x32_bf16(qa[0][0], kf0, acc0, 0,0,0);
    acc0 = __builtin_amdgcn_mfma_f32_16x16x32_bf16(qa[0][1], kf1, acc0, 0,0,0);
    acc1 = __builtin_amdgcn_mfma_f32_16x16x32_bf16(qa[1][0], kf0, acc1, 0,0,0);
    acc1 = __builtin_amdgcn_mfma_f32_16x16x32_bf16(qa[1][1], kf1, acc1, 0,0,0);
#pragma unroll
    for (int r = 0; r < 4; ++r) {
      rs[0][r] += mk ? __expf(acc0[r] * 0.125f) : 0.f;
      rs[1][r] += mk ? __expf(acc1[r] * 0.125f) : 0.f;
    }
  }
  // reduce across the 16 cols held per l4-group
#pragma unroll
  for (int rt = 0; rt < 2; ++rt)
#pragma unroll
    for (int r = 0; r < 4; ++r) {
#pragma unroll
      for (int o = 1; o < 16; o <<= 1)
        rs[rt][r] += __shfl_xor(rs[rt][r], o);
    }
  if (l15 == 0) {
#pragma unroll
    for (int rt = 0; rt < 2; ++rt)
#pragma unroll
      for (int r = 0; r < 4; ++r)
        sRed[wid][rt*16 + l4*4 + r] = rs[rt][r];
  }
  __syncthreads();
  if (tid < 32) {
    float t = 0.f;
#pragma unroll
    for (int w = 0; w < 8; ++w) t += sRed[w][tid];
    sSum[tid] = 1.0f / t;
  }
  __syncthreads();
  float rv[2][4];
#pragma unroll
  for (int rt = 0; rt < 2; ++rt)
#pragma unroll
    for (int r = 0; r < 4; ++r)
      rv[rt][r] = sSum[rt*16 + l4*4 + r];

  // ---------- pass 2: recompute scores per 256-col chunk, stream P, PV ----------
  const int rtw = wid >> 2, dt = wid & 3;
  f32x4 oacc = {0.f,0.f,0.f,0.f};

  for (int kc = 0; kc < 8; ++kc) {
    const int c0 = kc * 256;
    const int cw = c0 + wid * 32;
    const int mk0 = Mb[cw + l15];
    const int mk1 = Mb[cw + 16 + l15];

    bf16x8 kf[2][2];
#pragma unroll
    for (int ct = 0; ct < 2; ++ct) {
      const int col = cw + ct*16 + l15;
      if (PRE) {
        const unsigned short* kp = &Kb[(size_t)(bh * S_ + col) * D_ + l4*8];
        kf[ct][0] = __builtin_bit_cast(bf16x8, *(const us8*)kp);
        kf[ct][1] = __builtin_bit_cast(bf16x8, *(const us8*)(kp + 32));
      } else {
        const float* kp = Kh + (size_t)col * D_ + l4*8;
        kf[ct][0] = cvt8(kp); kf[ct][1] = cvt8(kp + 32);
      }
    }
    f32x4 acc[2][2];
#pragma unroll
    for (int rt = 0; rt < 2; ++rt)
#pragma unroll
      for (int ct = 0; ct < 2; ++ct) {
        f32x4 a = {0.f,0.f,0.f,0.f};
        a = __builtin_amdgcn_mfma_f32_16x16x32_bf16(qa[rt][0], kf[ct][0], a, 0,0,0);
        a = __builtin_amdgcn_mfma_f32_16x16x32_bf16(qa[rt][1], kf[ct][1], a, 0,0,0);
        acc[rt][ct] = a;
      }
    // normalize + stream P (fp32) + stash bf16 for PV
#pragma unroll
    for (int rt = 0; rt < 2; ++rt)
#pragma unroll
      for (int ct = 0; ct < 2; ++ct) {
        const int mk = ct ? mk1 : mk0;
#pragma unroll
        for (int r = 0; r < 4; ++r) {
          const int row = rt*16 + l4*4 + r;
          float p = mk ? __expf(acc[rt][ct][r] * 0.125f) * rv[rt][r] : 0.f;
          Ph[(size_t)row * S_ + cw + ct*16 + l15] = p;
          const int cs = wid*32 + ct*16 + l15;
          sP[kc & 1][row][cs ^ ((row & 7) << 3)] = f2bf(p);
        }
      }
    __syncthreads();
    // PV: wave (rtw, dt) owns a 16x16 O tile; K-depth 256 per chunk
#pragma unroll
    for (int s8 = 0; s8 < 8; ++s8) {
      const int e = s8*32 + l4*8;
      const int prow = rtw*16 + l15;
      us8 pa = *(const us8*)&sP[kc & 1][prow][e ^ ((prow & 7) << 3)];
      us8 vb;
      if (PRE) {
        vb = *(const us8*)&Vt[((size_t)(bh * D_ + dt*16 + l15)) * S_ + c0 + e];
      } else {
#pragma unroll
        for (int j = 0; j < 8; ++j)
          vb[j] = f2bf(Vh[(size_t)(c0 + e + j) * D_ + dt*16 + l15]);
      }
      oacc = __builtin_amdgcn_mfma_f32_16x16x32_bf16(
                 __builtin_bit_cast(bf16x8, pa),
                 __builtin_bit_cast(bf16x8, vb), oacc, 0,0,0);
    }
  }

#pragma unroll
  for (int r = 0; r < 4; ++r)
    Oh[(size_t)(rtw*16 + l4*4 + r) * D_ + dt*16 + l15] = oacc[r];
}

extern "C" void kernel_launch(void* const* d_in, const int* in_sizes, int n_in,
                              void* d_out, int out_size, void* d_ws, size_t ws_size,
                              hipStream_t stream) {
  const float* Q = (const float*)d_in[0];
  const float* K = (const float*)d_in[1];
  const float* V = (const float*)d_in[2];
  const int*   M = (const int*)d_in[3];
  float* outO = (float*)d_out;                                  // (B,H,S,D)
  float* outP = (float*)d_out + (size_t)4 * 16 * 2048 * 64;     // (B,H,S,S)

  const size_t bytesEach = (size_t)64 * 2048 * 64 * 2;          // 16 MiB per bf16 array
  const size_t need = 3 * bytesEach;

  if (ws_size >= need) {
    unsigned short* Vt = (unsigned short*)d_ws;
    unsigned short* Kb = (unsigned short*)((char*)d_ws + bytesEach);
    unsigned short* Qb = (unsigned short*)((char*)d_ws + 2 * bytesEach);
    const int n4 = 64 * 2048 * 64 / 4;
    cvt_bf16_kernel<<<dim3(2048), dim3(256), 0, stream>>>(K, Kb, n4);
    cvt_bf16_kernel<<<dim3(2048), dim3(256), 0, stream>>>(Q, Qb, n4);
    vtrans_kernel<<<dim3(2048), dim3(256), 0, stream>>>(V, Vt);
    attn_kernel<1><<<dim3(4096), dim3(512), 0, stream>>>(Q, K, V, M, Qb, Kb, Vt, outO, outP);
  } else {
    attn_kernel<0><<<dim3(4096), dim3(512), 0, stream>>>(Q, K, V, M,
        (const unsigned short*)nullptr, (const unsigned short*)nullptr,
        (const unsigned short*)nullptr, outO, outP);
  }
}